// Round 6
// baseline (191.052 us; speedup 1.0000x reference)
//
#include <hip/hip_runtime.h>
#include <hip/hip_bf16.h>
#include <cstdint>

typedef unsigned short u16;
typedef __attribute__((ext_vector_type(8))) short short8;
typedef __attribute__((ext_vector_type(4))) float f32x4;
typedef __attribute__((ext_vector_type(4))) unsigned short us4;

__device__ __forceinline__ u16 f2bf(float f) {
    union { float f; unsigned int i; } v; v.f = f;
    unsigned int x = v.i;
    unsigned int r = x + 0x7fffu + ((x >> 16) & 1u);  // RNE
    return (u16)(r >> 16);
}

enum { EPI_F32 = 0, EPI_BF16 = 1, EPI_EXP_RS = 3, EPI_F32_DIV_CB = 4, EPI_LMSM = 5 };

// C[M,N] = A[M,K] * B[N,K]^T (both K-contiguous). BK=64, 256 threads (4 waves
// 2x2). DOUBLE-BUFFERED K-loop: tile t+1's staging issued BEFORE tile t's
// compute, one __syncthreads per step. bf16 operands stage via async
// global_load_lds(16B) with XOR-8 swizzle applied on the GLOBAL address side
// (LDS lane mapping fixed: base + lane*16): chunk slot c_l of row r holds
// global chunk c_l^(r&7). Fragment reads invert the XOR -> bank-balanced
// ds_read_b128. f32 operands (AF32/BF32) reg-stage with T14 split: float4
// loads issued pre-compute, RNE + ds_write(16B) into the identical swizzled
// slot post-compute. A2x: optional second A source (q/k concat case).
template <int BM, int BN, int EPI, bool AF32, bool BF32>
__device__ __forceinline__ void gemm_body(
    char* __restrict__ smem,
    const void* __restrict__ Ax, const void* __restrict__ A2x,
    const void* __restrict__ Bx, void* __restrict__ Cv,
    int M, int N, int K, long sA, long sB, long sC,
    const float* __restrict__ biasCol, float* __restrict__ rowScale, float expScale,
    int m0, int n0, int z)
{
    constexpr int BK = 64;
    constexpr int MFRAG = (BM + 31) / 32;
    constexpr int NFRAG = BN / 32;
    constexpr int AG = (BM + 31) / 32;
    constexpr int BG = BN / 32;
    constexpr int TBUF = (BM + BN) * BK;

    const int tid = threadIdx.x;
    const int lane = tid & 63;
    const int quad = lane >> 4;
    const int l15 = lane & 15;
    const int w = tid >> 6;
    const int wm = w >> 1, wn = w & 1;

    const int r8 = tid >> 3;
    const int cl = tid & 7;
    const int cg = ((cl ^ (r8 & 7)) * 8);

    const u16* ap[AG];
    const float* apf[AG];
    if constexpr (AF32) {
        const float* base = (const float*)Ax;
        long mr = m0;
        if (A2x != nullptr && m0 >= (M >> 1)) { base = (const float*)A2x; mr = m0 - (M >> 1); }
        const float* Afb = base + (long)z * sA + (long)mr * K;
#pragma unroll
        for (int j = 0; j < AG; ++j) apf[j] = Afb + (long)(j * 32 + r8) * K + cg;
    } else {
        const u16* Ab = (const u16*)Ax + (long)z * sA + (long)m0 * K;
#pragma unroll
        for (int j = 0; j < AG; ++j) ap[j] = Ab + (long)(j * 32 + r8) * K + cg;
    }
    const u16* bp[BG];
    const float* bpf[BG];
    if constexpr (BF32) {
        const float* Bfb = (const float*)Bx + (long)z * sB + (long)n0 * K;
#pragma unroll
        for (int j = 0; j < BG; ++j) bpf[j] = Bfb + (long)(j * 32 + r8) * K + cg;
    } else {
        const u16* Bb = (const u16*)Bx + (long)z * sB + (long)n0 * K;
#pragma unroll
        for (int j = 0; j < BG; ++j) bp[j] = Bb + (long)(j * 32 + r8) * K + cg;
    }

    f32x4 acc[MFRAG][NFRAG] = {};
    const int sw = l15 & 7;
    u16* const base16 = (u16*)smem;
    const int NT = K / BK;

    // ---- prologue: stage tile 0 into buffer 0 ----
    {
        u16* As = base16;
        u16* Bs = base16 + BM * BK;
        if constexpr (!AF32) {
#pragma unroll
            for (int j = 0; j < AG; ++j) {
                __builtin_amdgcn_global_load_lds(
                    (const __attribute__((address_space(1))) void*)(ap[j]),
                    (__attribute__((address_space(3))) void*)(&As[(j * 32 + r8) * BK + cl * 8]),
                    16, 0, 0);
                ap[j] += BK;
            }
        } else {
#pragma unroll
            for (int j = 0; j < AG; ++j) {
                const float4 u0 = *(const float4*)(apf[j]);
                const float4 u1 = *(const float4*)(apf[j] + 4);
                short8 o;
                o[0] = (short)f2bf(u0.x); o[1] = (short)f2bf(u0.y);
                o[2] = (short)f2bf(u0.z); o[3] = (short)f2bf(u0.w);
                o[4] = (short)f2bf(u1.x); o[5] = (short)f2bf(u1.y);
                o[6] = (short)f2bf(u1.z); o[7] = (short)f2bf(u1.w);
                *(short8*)&As[(j * 32 + r8) * BK + cl * 8] = o;
                apf[j] += BK;
            }
        }
        if constexpr (!BF32) {
#pragma unroll
            for (int j = 0; j < BG; ++j) {
                __builtin_amdgcn_global_load_lds(
                    (const __attribute__((address_space(1))) void*)(bp[j]),
                    (__attribute__((address_space(3))) void*)(&Bs[(j * 32 + r8) * BK + cl * 8]),
                    16, 0, 0);
                bp[j] += BK;
            }
        } else {
#pragma unroll
            for (int j = 0; j < BG; ++j) {
                const float4 u0 = *(const float4*)(bpf[j]);
                const float4 u1 = *(const float4*)(bpf[j] + 4);
                short8 o;
                o[0] = (short)f2bf(u0.x); o[1] = (short)f2bf(u0.y);
                o[2] = (short)f2bf(u0.z); o[3] = (short)f2bf(u0.w);
                o[4] = (short)f2bf(u1.x); o[5] = (short)f2bf(u1.y);
                o[6] = (short)f2bf(u1.z); o[7] = (short)f2bf(u1.w);
                *(short8*)&Bs[(j * 32 + r8) * BK + cl * 8] = o;
                bpf[j] += BK;
            }
        }
    }
    __syncthreads();

    for (int t = 0; t < NT; ++t) {
        u16* Asc = base16 + (t & 1) * TBUF;
        u16* Bsc = Asc + BM * BK;
        u16* Asn = base16 + ((t + 1) & 1) * TBUF;
        u16* Bsn = Asn + BM * BK;
        const bool pf = (t + 1 < NT);

        float4 ra[AG][2];
        float4 rb[BG][2];
        if (pf) {
            if constexpr (!AF32) {
#pragma unroll
                for (int j = 0; j < AG; ++j) {
                    __builtin_amdgcn_global_load_lds(
                        (const __attribute__((address_space(1))) void*)(ap[j]),
                        (__attribute__((address_space(3))) void*)(&Asn[(j * 32 + r8) * BK + cl * 8]),
                        16, 0, 0);
                    ap[j] += BK;
                }
            } else {
#pragma unroll
                for (int j = 0; j < AG; ++j) {
                    ra[j][0] = *(const float4*)(apf[j]);
                    ra[j][1] = *(const float4*)(apf[j] + 4);
                    apf[j] += BK;
                }
            }
            if constexpr (!BF32) {
#pragma unroll
                for (int j = 0; j < BG; ++j) {
                    __builtin_amdgcn_global_load_lds(
                        (const __attribute__((address_space(1))) void*)(bp[j]),
                        (__attribute__((address_space(3))) void*)(&Bsn[(j * 32 + r8) * BK + cl * 8]),
                        16, 0, 0);
                    bp[j] += BK;
                }
            } else {
#pragma unroll
                for (int j = 0; j < BG; ++j) {
                    rb[j][0] = *(const float4*)(bpf[j]);
                    rb[j][1] = *(const float4*)(bpf[j] + 4);
                    bpf[j] += BK;
                }
            }
        }

#pragma unroll
        for (int ks = 0; ks < 2; ++ks) {
            short8 af[MFRAG], bfr[NFRAG];
#pragma unroll
            for (int i = 0; i < MFRAG; ++i)
                af[i] = *(const short8*)&Asc[(wm * (BM / 2) + i * 16 + l15) * BK +
                                             (((ks * 4 + quad) ^ sw) * 8)];
#pragma unroll
            for (int i = 0; i < NFRAG; ++i)
                bfr[i] = *(const short8*)&Bsc[(wn * (BN / 2) + i * 16 + l15) * BK +
                                              (((ks * 4 + quad) ^ sw) * 8)];
#pragma unroll
            for (int i = 0; i < MFRAG; ++i)
#pragma unroll
                for (int jn = 0; jn < NFRAG; ++jn)
                    acc[i][jn] = __builtin_amdgcn_mfma_f32_16x16x32_bf16(af[i], bfr[jn], acc[i][jn], 0, 0, 0);
        }

        if (pf) {
            if constexpr (AF32) {
#pragma unroll
                for (int j = 0; j < AG; ++j) {
                    short8 o;
                    o[0] = (short)f2bf(ra[j][0].x); o[1] = (short)f2bf(ra[j][0].y);
                    o[2] = (short)f2bf(ra[j][0].z); o[3] = (short)f2bf(ra[j][0].w);
                    o[4] = (short)f2bf(ra[j][1].x); o[5] = (short)f2bf(ra[j][1].y);
                    o[6] = (short)f2bf(ra[j][1].z); o[7] = (short)f2bf(ra[j][1].w);
                    *(short8*)&Asn[(j * 32 + r8) * BK + cl * 8] = o;
                }
            }
            if constexpr (BF32) {
#pragma unroll
                for (int j = 0; j < BG; ++j) {
                    short8 o;
                    o[0] = (short)f2bf(rb[j][0].x); o[1] = (short)f2bf(rb[j][0].y);
                    o[2] = (short)f2bf(rb[j][0].z); o[3] = (short)f2bf(rb[j][0].w);
                    o[4] = (short)f2bf(rb[j][1].x); o[5] = (short)f2bf(rb[j][1].y);
                    o[6] = (short)f2bf(rb[j][1].z); o[7] = (short)f2bf(rb[j][1].w);
                    *(short8*)&Bsn[(j * 32 + r8) * BK + cl * 8] = o;
                }
            }
        }
        __syncthreads();
    }

    // C/D layout: col=lane&15, row=quad*4+reg (m89/m91 verified).
    if constexpr (EPI == EPI_LMSM) {
        float* red = (float*)(base16 + 2 * TBUF);  // [2][BM]
        float ev[4][NFRAG];
#pragma unroll
        for (int r = 0; r < 4; ++r) {
            float s = 0.f;
#pragma unroll
            for (int jn = 0; jn < NFRAG; ++jn) {
                const int col = wn * (BN / 2) + jn * 16 + l15;
                float v = exp2f((acc[0][jn][r] + biasCol[col]) * expScale);
                ev[r][jn] = v; s += v;
            }
            s += __shfl_xor(s, 1); s += __shfl_xor(s, 2);
            s += __shfl_xor(s, 4); s += __shfl_xor(s, 8);
            if (l15 == 0) red[wn * BM + wm * 16 + quad * 4 + r] = s;
        }
        __syncthreads();
#pragma unroll
        for (int r = 0; r < 4; ++r) {
            const int mrow = wm * 16 + quad * 4 + r;
            const float inv = 1.0f / (red[mrow] + red[BM + mrow]);
            const long m = m0 + mrow;
#pragma unroll
            for (int jn = 0; jn < NFRAG; ++jn) {
                const int col = wn * (BN / 2) + jn * 16 + l15;
                ((u16*)Cv)[m * N + col] = f2bf(ev[r][jn] * inv);
            }
        }
        return;
    } else {
#pragma unroll
        for (int i = 0; i < MFRAG; ++i) {
            const int mb = m0 + wm * (BM / 2) + i * 16 + quad * 4;
#pragma unroll
            for (int r = 0; r < 4; ++r) {
                const int m = mb + r;
                float rin = 0.f;
                if constexpr (EPI == EPI_F32_DIV_CB) rin = 1.0f / rowScale[(long)z * M + m];
                float rowsum = 0.f;
#pragma unroll
                for (int jn = 0; jn < NFRAG; ++jn) {
                    const int col = n0 + wn * (BN / 2) + jn * 16 + l15;
                    float v = acc[i][jn][r];
                    if constexpr (EPI == EPI_EXP_RS) { v = exp2f(v * expScale); rowsum += v; }
                    if constexpr (EPI == EPI_F32_DIV_CB) v = v * rin + biasCol[col];
                    if constexpr (EPI == EPI_F32 || EPI == EPI_F32_DIV_CB)
                        ((float*)Cv)[(long)z * sC + (long)m * N + col] = v;
                    else
                        ((u16*)Cv)[(long)z * sC + (long)m * N + col] = f2bf(v);
                }
                if constexpr (EPI == EPI_EXP_RS) {
                    rowsum += __shfl_xor(rowsum, 1);
                    rowsum += __shfl_xor(rowsum, 2);
                    rowsum += __shfl_xor(rowsum, 4);
                    rowsum += __shfl_xor(rowsum, 8);
                    if (l15 == 0) atomicAdd(&rowScale[(long)z * M + m], rowsum);
                }
            }
        }
    }
}

// Thin grid wrapper for standalone GEMM launches (Ut).
template <int BM, int BN, int EPI, bool AF32, bool BF32>
__global__ void __launch_bounds__(256)
gemm_bt(const void* __restrict__ Ax, const void* __restrict__ A2x,
        const void* __restrict__ Bx, void* __restrict__ Cv,
        int M, int N, int K, long sA, long sB, long sC,
        const float* __restrict__ biasCol, float* __restrict__ rowScale, float expScale)
{
    extern __shared__ char smem[];
    gemm_body<BM, BN, EPI, AF32, BF32>(smem, Ax, A2x, Bx, Cv, M, N, K, sA, sB, sC,
                                       biasCol, rowScale, expScale,
                                       blockIdx.y * BM, blockIdx.x * BN, blockIdx.z);
}

// fused56: out[z] = diag(1/rowsum) exp(ql kl^T / 8) @ Ut^T + bocomb — P never
// materialized (flash-style). Per block: 64 q-rows x 128 out-cols; loop over
// 32 key-tiles (64 keys). ql A-frags live in REGISTERS for the whole kernel.
// Per tile: QK^T (8 MFMA, K=64) -> exp2 f32 -> in-register rowsum accum
// (full key range in one block: no atomics) -> P-tile to LDS as bf16 with the
// same XOR-8 swizzle as staging (PV A-frag reads = proven bank pattern) ->
// PV (16 MFMA) accumulating the SAME order as the old gemm6 (bit-identical).
// kl (256KB/z) and the block's Ut slice (1MB; blockIdx.x%8 == XCD -> one
// n-slice per XCD) are L2-resident: HBM traffic is out + first-touch only.
__global__ void __launch_bounds__(256)
fused56(const u16* __restrict__ qlkl, const u16* __restrict__ Ut,
        float* __restrict__ out, const float* __restrict__ bocomb)
{
    extern __shared__ char smem[];  // kl/U dbuf 2x24576 + P 8192 + red 512
    constexpr float SC = 0.18033688011112042f;  // log2(e)/8
    const int tid = threadIdx.x;
    const int lane = tid & 63;
    const int quad = lane >> 4;
    const int l15 = lane & 15;
    const int w = tid >> 6;
    const int wm = w >> 1, wn = w & 1;
    const int z = blockIdx.z;
    const int m0 = blockIdx.y * 64;
    const int n0 = blockIdx.x * 128;

    const int r8 = tid >> 3;
    const int cl = tid & 7;
    const int cg = ((cl ^ (r8 & 7)) * 8);
    const int sw = l15 & 7;

    u16* const pb = (u16*)(smem + 49152);
    float* const redf = (float*)(smem + 57344);

    // ql A-frags -> registers (rows m0+wm*32+i*16+l15, chunk ks*4+quad)
    const u16* qz = qlkl + (long)z * 131072 + (long)m0 * 64;
    short8 qf0a, qf0b, qf1a, qf1b;
    qf0a = *(const short8*)(qz + (wm * 32 + l15) * 64 + quad * 8);
    qf0b = *(const short8*)(qz + (wm * 32 + 16 + l15) * 64 + quad * 8);
    qf1a = *(const short8*)(qz + (wm * 32 + l15) * 64 + (4 + quad) * 8);
    qf1b = *(const short8*)(qz + (wm * 32 + 16 + l15) * 64 + (4 + quad) * 8);

    const u16* kp[2];
    const u16* up[4];
    {
        const u16* klz = qlkl + 262144 + (long)z * 131072;
#pragma unroll
        for (int j = 0; j < 2; ++j) kp[j] = klz + (long)(j * 32 + r8) * 64 + cg;
        const u16* uz = Ut + (long)z * 2097152 + (long)n0 * 2048;
#pragma unroll
        for (int j = 0; j < 4; ++j) up[j] = uz + (long)(j * 32 + r8) * 2048 + cg;
    }

    auto stage = [&](int bi) {
        char* bufn = smem + bi * 24576;
        u16* kls = (u16*)bufn;
        u16* us = (u16*)(bufn + 8192);
#pragma unroll
        for (int j = 0; j < 2; ++j) {
            __builtin_amdgcn_global_load_lds(
                (const __attribute__((address_space(1))) void*)(kp[j]),
                (__attribute__((address_space(3))) void*)(&kls[(j * 32 + r8) * 64 + cl * 8]),
                16, 0, 0);
            kp[j] += 4096;   // kl tiles are contiguous 64x64 blocks
        }
#pragma unroll
        for (int j = 0; j < 4; ++j) {
            __builtin_amdgcn_global_load_lds(
                (const __attribute__((address_space(1))) void*)(up[j]),
                (__attribute__((address_space(3))) void*)(&us[(j * 32 + r8) * 64 + cl * 8]),
                16, 0, 0);
            up[j] += 64;     // next k-slice of Ut rows
        }
    };

    f32x4 acc[2][4] = {};
    float rs[2][4] = {};

    stage(0);
    asm volatile("s_waitcnt vmcnt(0)" ::: "memory");
    __builtin_amdgcn_s_barrier();
    __builtin_amdgcn_sched_barrier(0);

    for (int t = 0; t < 32; ++t) {
        const int cur = t & 1;
        if (t + 1 < 32) stage(cur ^ 1);

        char* bufc = smem + cur * 24576;
        u16* klc = (u16*)bufc;
        u16* uc = (u16*)(bufc + 8192);

        // QK^T -> fresh per-tile scores (C[m, k_local])
        f32x4 pacc[2][2] = {};
#pragma unroll
        for (int ks = 0; ks < 2; ++ks) {
            short8 bk[2];
#pragma unroll
            for (int jn = 0; jn < 2; ++jn)
                bk[jn] = *(const short8*)&klc[(wn * 32 + jn * 16 + l15) * 64 +
                                              (((ks * 4 + quad) ^ sw) * 8)];
            const short8 qa = ks ? qf1a : qf0a;
            const short8 qb = ks ? qf1b : qf0b;
#pragma unroll
            for (int jn = 0; jn < 2; ++jn) {
                pacc[0][jn] = __builtin_amdgcn_mfma_f32_16x16x32_bf16(qa, bk[jn], pacc[0][jn], 0, 0, 0);
                pacc[1][jn] = __builtin_amdgcn_mfma_f32_16x16x32_bf16(qb, bk[jn], pacc[1][jn], 0, 0, 0);
            }
        }

        // exp2, rowsum accum, P -> LDS bf16 (swizzled for A-frag reads)
#pragma unroll
        for (int i = 0; i < 2; ++i)
#pragma unroll
            for (int r = 0; r < 4; ++r) {
                const int ml = wm * 32 + i * 16 + quad * 4 + r;
                const int mb8 = ml & 7;
#pragma unroll
                for (int jn = 0; jn < 2; ++jn) {
                    const int kl_ = wn * 32 + jn * 16 + l15;
                    const float v = exp2f(pacc[i][jn][r] * SC);
                    rs[i][r] += v;
                    pb[ml * 64 + ((((kl_ >> 3) ^ mb8)) << 3) + (kl_ & 7)] = f2bf(v);
                }
            }

        asm volatile("s_waitcnt lgkmcnt(0)" ::: "memory");
        __builtin_amdgcn_s_barrier();
        __builtin_amdgcn_sched_barrier(0);

        // PV: acc += P_tile @ U_tile^T  (same decomposition as old gemm6)
#pragma unroll
        for (int ks = 0; ks < 2; ++ks) {
            short8 pa[2], bu[4];
#pragma unroll
            for (int i = 0; i < 2; ++i)
                pa[i] = *(const short8*)&pb[(wm * 32 + i * 16 + l15) * 64 +
                                            (((ks * 4 + quad) ^ sw) * 8)];
#pragma unroll
            for (int jn = 0; jn < 4; ++jn)
                bu[jn] = *(const short8*)&uc[(wn * 64 + jn * 16 + l15) * 64 +
                                             (((ks * 4 + quad) ^ sw) * 8)];
#pragma unroll
            for (int i = 0; i < 2; ++i)
#pragma unroll
                for (int jn = 0; jn < 4; ++jn)
                    acc[i][jn] = __builtin_amdgcn_mfma_f32_16x16x32_bf16(pa[i], bu[jn], acc[i][jn], 0, 0, 0);
        }

        asm volatile("s_waitcnt vmcnt(0)" ::: "memory");
        __builtin_amdgcn_s_barrier();
        __builtin_amdgcn_sched_barrier(0);
    }

    // rowsum: reduce over l15 (16 k-cols/lane-group), then across wn via LDS
#pragma unroll
    for (int i = 0; i < 2; ++i)
#pragma unroll
        for (int r = 0; r < 4; ++r) {
            float s = rs[i][r];
            s += __shfl_xor(s, 1); s += __shfl_xor(s, 2);
            s += __shfl_xor(s, 4); s += __shfl_xor(s, 8);
            if (l15 == 0) redf[wn * 64 + wm * 32 + i * 16 + quad * 4 + r] = s;
        }
    __syncthreads();

#pragma unroll
    for (int i = 0; i < 2; ++i) {
        const int mb = m0 + wm * 32 + i * 16 + quad * 4;
#pragma unroll
        for (int r = 0; r < 4; ++r) {
            const int ml = wm * 32 + i * 16 + quad * 4 + r;
            const float rin = 1.0f / (redf[ml] + redf[64 + ml]);
            const int m = mb + r;
#pragma unroll
            for (int jn = 0; jn < 4; ++jn) {
                const int col = n0 + wn * 64 + jn * 16 + l15;
                out[(long)z * 2097152 + (long)m * 1024 + col] =
                    acc[i][jn][r] * rin + bocomb[col];
            }
        }
    }
}

// Fused launch A (768 blocks):
//   [0,256):   ql/kl landmark softmax (LMSM; q/k AND Wl read f32 directly)
//   [256,512): Wov = Wo(f32) @ WvT
//   [512,768): bocomb = bo + Wo @ bv (one wave per row; consumed by fused56)
__global__ void __launch_bounds__(256)
fused23(const float* __restrict__ query, const float* __restrict__ key,
        const float* __restrict__ Wl, u16* __restrict__ qlkl,
        const float* __restrict__ bl,
        const float* __restrict__ Wo, const u16* __restrict__ WvT, u16* __restrict__ Wov,
        const float* __restrict__ bv, const float* __restrict__ bo,
        float* __restrict__ bocomb)
{
    extern __shared__ char smem[];
    const int b = blockIdx.x;
    if (b < 256) {
        gemm_body<32, 64, EPI_LMSM, true, true>(smem, query, key, Wl, qlkl,
            8192, 64, 1024, 0, 0, 0, bl, nullptr, 0.18033688011112042f,
            b * 32, 0, 0);
    } else if (b < 512) {
        const int t = b - 256;
        gemm_body<64, 64, EPI_BF16, true, false>(smem, Wo, nullptr, WvT, Wov,
            1024, 1024, 1024, 0, 0, 0, nullptr, nullptr, 0.f,
            (t >> 4) * 64, (t & 15) * 64, 0);
    } else {
        const int row = (b - 512) * 4 + (threadIdx.x >> 6);
        const int lane = threadIdx.x & 63;
        float s = 0.f;
#pragma unroll
        for (int i = 0; i < 16; ++i) s += Wo[(long)row * 1024 + i * 64 + lane] * bv[i * 64 + lane];
        for (int o = 32; o; o >>= 1) s += __shfl_xor(s, o, 64);
        if (lane == 0) bocomb[row] = bo[row] + s;
    }
}

// Prep: WvT[e,d] = bf16(Wv[d,e]) via padded LDS tile (256 blocks).
__global__ void __launch_bounds__(256)
prep_wvt(const float* __restrict__ Wv, u16* __restrict__ WvT)
{
    __shared__ float t[64][65];
    const int bx = blockIdx.x & 15, by = blockIdx.x >> 4;
    const int tid = threadIdx.x;
#pragma unroll
    for (int p = 0; p < 16; ++p) {
        int idx = p * 256 + tid;
        int r = idx >> 6, c = idx & 63;
        t[r][c] = Wv[(long)(by * 64 + r) * 1024 + bx * 64 + c];
    }
    __syncthreads();
#pragma unroll
    for (int p = 0; p < 16; ++p) {
        int idx = p * 256 + tid;
        int c = idx >> 6, r = idx & 63;
        WvT[(long)(bx * 64 + c) * 1024 + by * 64 + r] = f2bf(t[r][c]);
    }
}

extern "C" void kernel_launch(void* const* d_in, const int* in_sizes, int n_in,
                              void* d_out, int out_size, void* d_ws, size_t ws_size,
                              hipStream_t stream)
{
    const float* query = (const float*)d_in[0];
    const float* key   = (const float*)d_in[1];
    const float* value = (const float*)d_in[2];
    const float* Wv    = (const float*)d_in[3];
    const float* bv    = (const float*)d_in[4];
    const float* Wl    = (const float*)d_in[5];
    const float* bl    = (const float*)d_in[6];
    const float* Wo    = (const float*)d_in[7];
    const float* bo    = (const float*)d_in[8];
    float* out = (float*)d_out;

    // B=2, L=2048, E=1024, M_land=64.
    // out = diag(1/rowsum(P)) P value Wov^T + 1*(Wo bv + bo)^T,
    //   P = exp(ql kl^T / 8),  Wov = Wo @ Wv,  Ut = Wov @ value^T.
    // P is NEVER materialized: fused56 computes exp(ql kl^T) tile-wise and
    // multiplies into Ut^T flash-style (rowsum in-register, no atomics).
    // DAG: prep(WvT) -> {lmsm, wov, bocomb}(fused23) -> ut -> fused56.
    char* ws = (char*)d_ws;
    u16*   WvT    = (u16*)  (ws + 27394048);   // [1024(e),1024(d)]
    u16*   Wov    = (u16*)  (ws + 29491200);   // [1024(o),1024(e)]
    u16*   qlkl   = (u16*)  (ws + 31588352);   // [8192,64] (ql then kl)
    u16*   Ut     = (u16*)  (ws + 32636928);   // [2,1024(o),2048(k)]
    float* bocomb = (float*)(ws + 57819136);   // [1024]

    // 1) prep (Wv transpose-cast)
    prep_wvt<<<dim3(256), 256, 0, stream>>>(Wv, WvT);

    // 2+3) ql/kl landmark softmax || Wov = Wo @ Wv || bocomb
    fused23<<<dim3(768), 256, 32768, stream>>>(query, key, Wl, qlkl, bl,
                                               Wo, WvT, Wov, bv, bo, bocomb);

    // 4) Ut[z] = Wov @ value[z]^T (value read f32, dbuf)
    gemm_bt<128, 64, EPI_BF16, false, true><<<dim3(32, 8, 2), 256, 49152, stream>>>(
        Wov, nullptr, value, Ut, 1024, 2048, 1024, 0, 2097152, 2097152,
        nullptr, nullptr, 0.f);

    // 5+6) out = flash(P @ Ut^T) + bocomb
    fused56<<<dim3(8, 32, 2), 256, 57856, stream>>>(qlkl, Ut, out, bocomb);
}

// Round 8
// 168.397 us; speedup vs baseline: 1.1345x; 1.1345x over previous
//
#include <hip/hip_runtime.h>
#include <hip/hip_bf16.h>
#include <cstdint>

typedef unsigned short u16;
typedef __attribute__((ext_vector_type(8))) short short8;
typedef __attribute__((ext_vector_type(4))) float f32x4;
typedef __attribute__((ext_vector_type(4))) unsigned short us4;

__device__ __forceinline__ u16 f2bf(float f) {
    union { float f; unsigned int i; } v; v.f = f;
    unsigned int x = v.i;
    unsigned int r = x + 0x7fffu + ((x >> 16) & 1u);  // RNE
    return (u16)(r >> 16);
}

enum { EPI_F32 = 0, EPI_BF16 = 1, EPI_EXP_RS = 3, EPI_F32_DIV_CB = 4, EPI_LMSM = 5 };

// C[M,N] = A[M,K] * B[N,K]^T (both K-contiguous). BK=64, 256 threads (4 waves
// 2x2). DOUBLE-BUFFERED K-loop: tile t+1's staging issued BEFORE tile t's
// compute, one __syncthreads per step. bf16 operands stage via async
// global_load_lds(16B) with XOR-8 swizzle applied on the GLOBAL address side
// (LDS lane mapping fixed: base + lane*16): chunk slot c_l of row r holds
// global chunk c_l^(r&7). Fragment reads invert the XOR -> bank-balanced
// ds_read_b128. f32 operands (AF32/BF32) reg-stage with T14 split: float4
// loads issued pre-compute, RNE + ds_write(16B) into the identical swizzled
// slot post-compute. A2x: optional second A source (q/k concat case).
template <int BM, int BN, int EPI, bool AF32, bool BF32>
__device__ __forceinline__ void gemm_body(
    char* __restrict__ smem,
    const void* __restrict__ Ax, const void* __restrict__ A2x,
    const void* __restrict__ Bx, void* __restrict__ Cv,
    int M, int N, int K, long sA, long sB, long sC,
    const float* __restrict__ biasCol, float* __restrict__ rowScale, float expScale,
    int m0, int n0, int z)
{
    constexpr int BK = 64;
    constexpr int MFRAG = (BM + 31) / 32;
    constexpr int NFRAG = BN / 32;
    constexpr int AG = (BM + 31) / 32;
    constexpr int BG = BN / 32;
    constexpr int TBUF = (BM + BN) * BK;

    const int tid = threadIdx.x;
    const int lane = tid & 63;
    const int quad = lane >> 4;
    const int l15 = lane & 15;
    const int w = tid >> 6;
    const int wm = w >> 1, wn = w & 1;

    const int r8 = tid >> 3;
    const int cl = tid & 7;
    const int cg = ((cl ^ (r8 & 7)) * 8);

    const u16* ap[AG];
    const float* apf[AG];
    if constexpr (AF32) {
        const float* base = (const float*)Ax;
        long mr = m0;
        if (A2x != nullptr && m0 >= (M >> 1)) { base = (const float*)A2x; mr = m0 - (M >> 1); }
        const float* Afb = base + (long)z * sA + (long)mr * K;
#pragma unroll
        for (int j = 0; j < AG; ++j) apf[j] = Afb + (long)(j * 32 + r8) * K + cg;
    } else {
        const u16* Ab = (const u16*)Ax + (long)z * sA + (long)m0 * K;
#pragma unroll
        for (int j = 0; j < AG; ++j) ap[j] = Ab + (long)(j * 32 + r8) * K + cg;
    }
    const u16* bp[BG];
    const float* bpf[BG];
    if constexpr (BF32) {
        const float* Bfb = (const float*)Bx + (long)z * sB + (long)n0 * K;
#pragma unroll
        for (int j = 0; j < BG; ++j) bpf[j] = Bfb + (long)(j * 32 + r8) * K + cg;
    } else {
        const u16* Bb = (const u16*)Bx + (long)z * sB + (long)n0 * K;
#pragma unroll
        for (int j = 0; j < BG; ++j) bp[j] = Bb + (long)(j * 32 + r8) * K + cg;
    }

    f32x4 acc[MFRAG][NFRAG] = {};
    const int sw = l15 & 7;
    u16* const base16 = (u16*)smem;
    const int NT = K / BK;

    // ---- prologue: stage tile 0 into buffer 0 ----
    {
        u16* As = base16;
        u16* Bs = base16 + BM * BK;
        if constexpr (!AF32) {
#pragma unroll
            for (int j = 0; j < AG; ++j) {
                __builtin_amdgcn_global_load_lds(
                    (const __attribute__((address_space(1))) void*)(ap[j]),
                    (__attribute__((address_space(3))) void*)(&As[(j * 32 + r8) * BK + cl * 8]),
                    16, 0, 0);
                ap[j] += BK;
            }
        } else {
#pragma unroll
            for (int j = 0; j < AG; ++j) {
                const float4 u0 = *(const float4*)(apf[j]);
                const float4 u1 = *(const float4*)(apf[j] + 4);
                short8 o;
                o[0] = (short)f2bf(u0.x); o[1] = (short)f2bf(u0.y);
                o[2] = (short)f2bf(u0.z); o[3] = (short)f2bf(u0.w);
                o[4] = (short)f2bf(u1.x); o[5] = (short)f2bf(u1.y);
                o[6] = (short)f2bf(u1.z); o[7] = (short)f2bf(u1.w);
                *(short8*)&As[(j * 32 + r8) * BK + cl * 8] = o;
                apf[j] += BK;
            }
        }
        if constexpr (!BF32) {
#pragma unroll
            for (int j = 0; j < BG; ++j) {
                __builtin_amdgcn_global_load_lds(
                    (const __attribute__((address_space(1))) void*)(bp[j]),
                    (__attribute__((address_space(3))) void*)(&Bs[(j * 32 + r8) * BK + cl * 8]),
                    16, 0, 0);
                bp[j] += BK;
            }
        } else {
#pragma unroll
            for (int j = 0; j < BG; ++j) {
                const float4 u0 = *(const float4*)(bpf[j]);
                const float4 u1 = *(const float4*)(bpf[j] + 4);
                short8 o;
                o[0] = (short)f2bf(u0.x); o[1] = (short)f2bf(u0.y);
                o[2] = (short)f2bf(u0.z); o[3] = (short)f2bf(u0.w);
                o[4] = (short)f2bf(u1.x); o[5] = (short)f2bf(u1.y);
                o[6] = (short)f2bf(u1.z); o[7] = (short)f2bf(u1.w);
                *(short8*)&Bs[(j * 32 + r8) * BK + cl * 8] = o;
                bpf[j] += BK;
            }
        }
    }
    __syncthreads();

    for (int t = 0; t < NT; ++t) {
        u16* Asc = base16 + (t & 1) * TBUF;
        u16* Bsc = Asc + BM * BK;
        u16* Asn = base16 + ((t + 1) & 1) * TBUF;
        u16* Bsn = Asn + BM * BK;
        const bool pf = (t + 1 < NT);

        float4 ra[AG][2];
        float4 rb[BG][2];
        if (pf) {
            if constexpr (!AF32) {
#pragma unroll
                for (int j = 0; j < AG; ++j) {
                    __builtin_amdgcn_global_load_lds(
                        (const __attribute__((address_space(1))) void*)(ap[j]),
                        (__attribute__((address_space(3))) void*)(&Asn[(j * 32 + r8) * BK + cl * 8]),
                        16, 0, 0);
                    ap[j] += BK;
                }
            } else {
#pragma unroll
                for (int j = 0; j < AG; ++j) {
                    ra[j][0] = *(const float4*)(apf[j]);
                    ra[j][1] = *(const float4*)(apf[j] + 4);
                    apf[j] += BK;
                }
            }
            if constexpr (!BF32) {
#pragma unroll
                for (int j = 0; j < BG; ++j) {
                    __builtin_amdgcn_global_load_lds(
                        (const __attribute__((address_space(1))) void*)(bp[j]),
                        (__attribute__((address_space(3))) void*)(&Bsn[(j * 32 + r8) * BK + cl * 8]),
                        16, 0, 0);
                    bp[j] += BK;
                }
            } else {
#pragma unroll
                for (int j = 0; j < BG; ++j) {
                    rb[j][0] = *(const float4*)(bpf[j]);
                    rb[j][1] = *(const float4*)(bpf[j] + 4);
                    bpf[j] += BK;
                }
            }
        }

#pragma unroll
        for (int ks = 0; ks < 2; ++ks) {
            short8 af[MFRAG], bfr[NFRAG];
#pragma unroll
            for (int i = 0; i < MFRAG; ++i)
                af[i] = *(const short8*)&Asc[(wm * (BM / 2) + i * 16 + l15) * BK +
                                             (((ks * 4 + quad) ^ sw) * 8)];
#pragma unroll
            for (int i = 0; i < NFRAG; ++i)
                bfr[i] = *(const short8*)&Bsc[(wn * (BN / 2) + i * 16 + l15) * BK +
                                              (((ks * 4 + quad) ^ sw) * 8)];
#pragma unroll
            for (int i = 0; i < MFRAG; ++i)
#pragma unroll
                for (int jn = 0; jn < NFRAG; ++jn)
                    acc[i][jn] = __builtin_amdgcn_mfma_f32_16x16x32_bf16(af[i], bfr[jn], acc[i][jn], 0, 0, 0);
        }

        if (pf) {
            if constexpr (AF32) {
#pragma unroll
                for (int j = 0; j < AG; ++j) {
                    short8 o;
                    o[0] = (short)f2bf(ra[j][0].x); o[1] = (short)f2bf(ra[j][0].y);
                    o[2] = (short)f2bf(ra[j][0].z); o[3] = (short)f2bf(ra[j][0].w);
                    o[4] = (short)f2bf(ra[j][1].x); o[5] = (short)f2bf(ra[j][1].y);
                    o[6] = (short)f2bf(ra[j][1].z); o[7] = (short)f2bf(ra[j][1].w);
                    *(short8*)&Asn[(j * 32 + r8) * BK + cl * 8] = o;
                }
            }
            if constexpr (BF32) {
#pragma unroll
                for (int j = 0; j < BG; ++j) {
                    short8 o;
                    o[0] = (short)f2bf(rb[j][0].x); o[1] = (short)f2bf(rb[j][0].y);
                    o[2] = (short)f2bf(rb[j][0].z); o[3] = (short)f2bf(rb[j][0].w);
                    o[4] = (short)f2bf(rb[j][1].x); o[5] = (short)f2bf(rb[j][1].y);
                    o[6] = (short)f2bf(rb[j][1].z); o[7] = (short)f2bf(rb[j][1].w);
                    *(short8*)&Bsn[(j * 32 + r8) * BK + cl * 8] = o;
                }
            }
        }
        __syncthreads();
    }

    // C/D layout: col=lane&15, row=quad*4+reg (m89/m91 verified).
    if constexpr (EPI == EPI_LMSM) {
        float* red = (float*)(base16 + 2 * TBUF);  // [2][BM]
        float ev[4][NFRAG];
#pragma unroll
        for (int r = 0; r < 4; ++r) {
            float s = 0.f;
#pragma unroll
            for (int jn = 0; jn < NFRAG; ++jn) {
                const int col = wn * (BN / 2) + jn * 16 + l15;
                float v = exp2f((acc[0][jn][r] + biasCol[col]) * expScale);
                ev[r][jn] = v; s += v;
            }
            s += __shfl_xor(s, 1); s += __shfl_xor(s, 2);
            s += __shfl_xor(s, 4); s += __shfl_xor(s, 8);
            if (l15 == 0) red[wn * BM + wm * 16 + quad * 4 + r] = s;
        }
        __syncthreads();
#pragma unroll
        for (int r = 0; r < 4; ++r) {
            const int mrow = wm * 16 + quad * 4 + r;
            const float inv = 1.0f / (red[mrow] + red[BM + mrow]);
            const long m = m0 + mrow;
#pragma unroll
            for (int jn = 0; jn < NFRAG; ++jn) {
                const int col = wn * (BN / 2) + jn * 16 + l15;
                ((u16*)Cv)[m * N + col] = f2bf(ev[r][jn] * inv);
            }
        }
        return;
    } else {
#pragma unroll
        for (int i = 0; i < MFRAG; ++i) {
            const int mb = m0 + wm * (BM / 2) + i * 16 + quad * 4;
#pragma unroll
            for (int r = 0; r < 4; ++r) {
                const int m = mb + r;
                float rin = 0.f;
                if constexpr (EPI == EPI_F32_DIV_CB) rin = 1.0f / rowScale[(long)z * M + m];
                float rowsum = 0.f;
#pragma unroll
                for (int jn = 0; jn < NFRAG; ++jn) {
                    const int col = n0 + wn * (BN / 2) + jn * 16 + l15;
                    float v = acc[i][jn][r];
                    if constexpr (EPI == EPI_EXP_RS) { v = exp2f(v * expScale); rowsum += v; }
                    if constexpr (EPI == EPI_F32_DIV_CB) v = v * rin + biasCol[col];
                    if constexpr (EPI == EPI_F32 || EPI == EPI_F32_DIV_CB)
                        ((float*)Cv)[(long)z * sC + (long)m * N + col] = v;
                    else
                        ((u16*)Cv)[(long)z * sC + (long)m * N + col] = f2bf(v);
                }
                if constexpr (EPI == EPI_EXP_RS) {
                    rowsum += __shfl_xor(rowsum, 1);
                    rowsum += __shfl_xor(rowsum, 2);
                    rowsum += __shfl_xor(rowsum, 4);
                    rowsum += __shfl_xor(rowsum, 8);
                    if (l15 == 0) atomicAdd(&rowScale[(long)z * M + m], rowsum);
                }
            }
        }
    }
}

// gemm6 (512 threads): out[z] = diag(1/rsc) P[z] @ Ut[z]^T + bocomb, f32 out.
// Same 64x128 tile / BK=64 / dbuf / barrier structure as gemm_body, but 8
// waves (2 row-halves x 4 col-quarters, each owning 32x32) -> 2 blocks/CU x
// 8 waves = 16 waves/CU (vs 8): double the latency-hiding TLP at identical
// HBM traffic. Each 16x16 output tile sees the identical MFMA accumulation
// sequence as the 256-thread version -> bit-identical results.
__global__ void __launch_bounds__(512)
gemm6_512(const u16* __restrict__ Pm, const u16* __restrict__ Ut, float* __restrict__ out,
          const float* __restrict__ bocomb, const float* __restrict__ rsc)
{
    extern __shared__ char smem[];          // 2 x 24576 B
    constexpr int BK = 64, NT = 32;
    constexpr int TB = (64 + 128) * BK;     // u16 elems per buffer
    const int tid = threadIdx.x;
    const int lane = tid & 63;
    const int quad = lane >> 4;
    const int l15 = lane & 15;
    const int w = tid >> 6;                 // 0..7
    const int wm = w & 1, wn = w >> 1;      // wave tile: rows wm*32, cols wn*32
    const int z = blockIdx.z;
    const int m0 = blockIdx.y * 64;
    const int n0 = blockIdx.x * 128;

    const int r8 = tid >> 3;                // 0..63 staging row
    const int cl = tid & 7;
    const int cg = ((cl ^ (r8 & 7)) * 8);
    const int sw = l15 & 7;

    const u16* ap = Pm + (long)z * 4194304 + (long)(m0 + r8) * 2048 + cg;
    const u16* bp[2];
#pragma unroll
    for (int j = 0; j < 2; ++j)
        bp[j] = Ut + (long)z * 2097152 + (long)(n0 + j * 64 + r8) * 2048 + cg;

    u16* const base16 = (u16*)smem;
    auto stage = [&](int bi) {
        u16* As = base16 + bi * TB;
        u16* Bs = As + 64 * BK;
        __builtin_amdgcn_global_load_lds(
            (const __attribute__((address_space(1))) void*)(ap),
            (__attribute__((address_space(3))) void*)(&As[r8 * BK + cl * 8]),
            16, 0, 0);
        ap += BK;
#pragma unroll
        for (int j = 0; j < 2; ++j) {
            __builtin_amdgcn_global_load_lds(
                (const __attribute__((address_space(1))) void*)(bp[j]),
                (__attribute__((address_space(3))) void*)(&Bs[(j * 64 + r8) * BK + cl * 8]),
                16, 0, 0);
            bp[j] += BK;
        }
    };

    f32x4 acc[2][2] = {};

    stage(0);
    __syncthreads();

    for (int t = 0; t < NT; ++t) {
        u16* Asc = base16 + (t & 1) * TB;
        u16* Bsc = Asc + 64 * BK;
        if (t + 1 < NT) stage((t + 1) & 1);

#pragma unroll
        for (int ks = 0; ks < 2; ++ks) {
            short8 af[2], bu[2];
#pragma unroll
            for (int i = 0; i < 2; ++i)
                af[i] = *(const short8*)&Asc[(wm * 32 + i * 16 + l15) * BK +
                                             (((ks * 4 + quad) ^ sw) * 8)];
#pragma unroll
            for (int jn = 0; jn < 2; ++jn)
                bu[jn] = *(const short8*)&Bsc[(wn * 32 + jn * 16 + l15) * BK +
                                              (((ks * 4 + quad) ^ sw) * 8)];
#pragma unroll
            for (int i = 0; i < 2; ++i)
#pragma unroll
                for (int jn = 0; jn < 2; ++jn)
                    acc[i][jn] = __builtin_amdgcn_mfma_f32_16x16x32_bf16(af[i], bu[jn], acc[i][jn], 0, 0, 0);
        }
        __syncthreads();
    }

#pragma unroll
    for (int i = 0; i < 2; ++i) {
        const int mb = m0 + wm * 32 + i * 16 + quad * 4;
#pragma unroll
        for (int r = 0; r < 4; ++r) {
            const int m = mb + r;
            const float rin = 1.0f / rsc[z * 2048 + m];
#pragma unroll
            for (int jn = 0; jn < 2; ++jn) {
                const int col = n0 + wn * 32 + jn * 16 + l15;
                out[(long)z * 2097152 + (long)m * 1024 + col] =
                    acc[i][jn][r] * rin + bocomb[col];
            }
        }
    }
}

// Fused launch A (784 blocks):
//   [0,256):   ql/kl landmark softmax (LMSM; q/k AND Wl read f32 directly)
//   [256,512): Wov = Wo(f32) @ WvT
//   [512,768): bocomb = bo + Wo @ bv (one wave per row; consumed by gemm6)
//   [768,784): zero rsc (consumed by fused45)
__global__ void __launch_bounds__(256)
fused23(const float* __restrict__ query, const float* __restrict__ key,
        const float* __restrict__ Wl, u16* __restrict__ qlkl,
        const float* __restrict__ bl,
        const float* __restrict__ Wo, const u16* __restrict__ WvT, u16* __restrict__ Wov,
        const float* __restrict__ bv, const float* __restrict__ bo,
        float* __restrict__ rsc, float* __restrict__ bocomb)
{
    extern __shared__ char smem[];
    const int b = blockIdx.x;
    if (b < 256) {
        gemm_body<32, 64, EPI_LMSM, true, true>(smem, query, key, Wl, qlkl,
            8192, 64, 1024, 0, 0, 0, bl, nullptr, 0.18033688011112042f,
            b * 32, 0, 0);
    } else if (b < 512) {
        const int t = b - 256;
        gemm_body<64, 64, EPI_BF16, true, false>(smem, Wo, nullptr, WvT, Wov,
            1024, 1024, 1024, 0, 0, 0, nullptr, nullptr, 0.f,
            (t >> 4) * 64, (t & 15) * 64, 0);
    } else if (b < 768) {
        const int row = (b - 512) * 4 + (threadIdx.x >> 6);
        const int lane = threadIdx.x & 63;
        float s = 0.f;
#pragma unroll
        for (int i = 0; i < 16; ++i) s += Wo[(long)row * 1024 + i * 64 + lane] * bv[i * 64 + lane];
        for (int o = 32; o; o >>= 1) s += __shfl_xor(s, o, 64);
        if (lane == 0) bocomb[row] = bo[row] + s;
    } else {
        rsc[(b - 768) * 256 + threadIdx.x] = 0.f;
    }
}

// Fused launch B: blocks [0,512)    = Ut[z] = Wov @ value[z]^T (value read f32);
//                 blocks [512,1024) = P[z] = exp(ql kl^T / 8) + row-sum atomics.
__global__ void __launch_bounds__(256)
fused45(const u16* __restrict__ Wov, const float* __restrict__ value, u16* __restrict__ Ut,
        const u16* __restrict__ qlkl, u16* __restrict__ Pm, float* __restrict__ rsc)
{
    extern __shared__ char smem[];
    const int b = blockIdx.x;
    if (b < 512) {
        const int x = b & 31, y = (b >> 5) & 7, z = b >> 8;
        gemm_body<128, 64, EPI_BF16, false, true>(smem, Wov, nullptr, value, Ut,
            1024, 2048, 1024, 0, 2097152, 2097152, nullptr, nullptr, 0.f,
            y * 128, x * 64, z);
    } else {
        const int t = b - 512;
        const int x = t & 15, y = (t >> 4) & 15, z = t >> 8;
        gemm_body<128, 128, EPI_EXP_RS, false, false>(smem, qlkl, nullptr, qlkl + 262144, Pm,
            2048, 2048, 64, 131072, 131072, 4194304, nullptr, rsc, 0.18033688011112042f,
            y * 128, x * 128, z);
    }
}

// Prep: WvT[e,d] = bf16(Wv[d,e]) via padded LDS tile (256 blocks).
__global__ void __launch_bounds__(256)
prep_wvt(const float* __restrict__ Wv, u16* __restrict__ WvT)
{
    __shared__ float t[64][65];
    const int bx = blockIdx.x & 15, by = blockIdx.x >> 4;
    const int tid = threadIdx.x;
#pragma unroll
    for (int p = 0; p < 16; ++p) {
        int idx = p * 256 + tid;
        int r = idx >> 6, c = idx & 63;
        t[r][c] = Wv[(long)(by * 64 + r) * 1024 + bx * 64 + c];
    }
    __syncthreads();
#pragma unroll
    for (int p = 0; p < 16; ++p) {
        int idx = p * 256 + tid;
        int c = idx >> 6, r = idx & 63;
        WvT[(long)(bx * 64 + c) * 1024 + by * 64 + r] = f2bf(t[r][c]);
    }
}

extern "C" void kernel_launch(void* const* d_in, const int* in_sizes, int n_in,
                              void* d_out, int out_size, void* d_ws, size_t ws_size,
                              hipStream_t stream)
{
    const float* query = (const float*)d_in[0];
    const float* key   = (const float*)d_in[1];
    const float* value = (const float*)d_in[2];
    const float* Wv    = (const float*)d_in[3];
    const float* bv    = (const float*)d_in[4];
    const float* Wl    = (const float*)d_in[5];
    const float* bl    = (const float*)d_in[6];
    const float* Wo    = (const float*)d_in[7];
    const float* bo    = (const float*)d_in[8];
    float* out = (float*)d_out;

    // B=2, L=2048, E=1024, M_land=64.
    // out = diag(1/rowsum(P)) P value Wov^T + 1*(Wo bv + bo)^T,
    //   P = exp(ql kl^T / 8),  Wov = Wo @ Wv,  Ut = Wov @ value^T.
    // q,k,value,Wo,Wl consumed as f32 directly (cast fused into GEMM staging).
    // DAG: prep(WvT) -> {lmsm, wov, bocomb, rsc0}(fused23)
    //      -> {ut, p}(fused45) -> out(gemm6_512).
    char* ws = (char*)d_ws;
    u16*   WvT    = (u16*)  (ws + 27394048);   // [1024(e),1024(d)]
    u16*   Wov    = (u16*)  (ws + 29491200);   // [1024(o),1024(e)]
    u16*   qlkl   = (u16*)  (ws + 31588352);   // [8192,64] (ql then kl)
    u16*   Ut     = (u16*)  (ws + 32636928);   // [2,1024(o),2048(k)]
    u16*   Pm     = (u16*)  (ws + 41025536);   // [2,2048,2048]
    float* rsc    = (float*)(ws + 57802752);   // [2,2048] row sums of P
    float* bocomb = (float*)(ws + 57819136);   // [1024]

    // 1) prep (Wv transpose-cast)
    prep_wvt<<<dim3(256), 256, 0, stream>>>(Wv, WvT);

    // 2+3) ql/kl landmark softmax || Wov = Wo @ Wv || bocomb || rsc zero
    fused23<<<dim3(784), 256, 32768, stream>>>(query, key, Wl, qlkl, bl,
                                               Wo, WvT, Wov, bv, bo, rsc, bocomb);

    // 4+5) Ut[z] = Wov @ value[z]^T  ||  P[z] = exp(ql kl^T/8) + rowsums
    fused45<<<dim3(1024), 256, 49152, stream>>>(Wov, value, Ut, qlkl, Pm, rsc);

    // 6) out[z] = diag(1/rsc) P[z] @ Ut[z]^T + bocomb -> f32 (512 threads)
    gemm6_512<<<dim3(8, 32, 2), 512, 49152, stream>>>(Pm, Ut, out, bocomb, rsc);
}